// Round 9
// baseline (135.331 us; speedup 1.0000x reference)
//
#include <hip/hip_runtime.h>

// Problem constants (from reference)
#define T_TOKENS 4096      // B*C = 4*1024
#define D_DIM    2048
#define NEXP     8
#define CAP      1280      // floor(2 * 1.25 * 4096 / 8), already even
#define NSLOTS   (NEXP * CAP)   // 10240

// gating geometry
#define GATE_TPB   512                       // 8 waves
#define GATE_TPW   2                         // tokens per wave
#define GATE_TPBK  16                        // tokens per block
#define GATE_BLOCKS (T_TOKENS / GATE_TPBK)   // 256
#define GCHUNK     512                       // floats of D per LDS stage
#define GCHUNK4    (GCHUNK / 4)              // 128 f32x4
#define NCHUNK     (D_DIM / GCHUNK)          // 4

// native 16-byte vector type
typedef float f32x4 __attribute__((ext_vector_type(4)));

__device__ __forceinline__ float dot4(f32x4 a, f32x4 b) {
    return a.x * b.x + a.y * b.y + a.z * b.z + a.w * b.w;
}

// ---------------------------------------------------------------------------
// Kernel 1: gating with LDS-staged weights. 256 blocks x 512 threads.
// Each block handles 16 tokens (2 per wave). Weights (w_g + w_noise) are
// staged through LDS in 32 KB chunks -> L2 weight traffic drops 16x vs the
// one-wave-per-token version; each LDS read feeds 2 tokens' FMAs.
// ---------------------------------------------------------------------------
__global__ void gating_kernel(const float* __restrict__ x,
                              const float* __restrict__ noise,
                              const float* __restrict__ w_g,
                              const float* __restrict__ w_noise,
                              int*   __restrict__ top_idx,    // [2*T] slot-major
                              float* __restrict__ top_prob)   // [2*T] slot-major
{
    __shared__ f32x4 s_wg[NEXP][GCHUNK4];   // 16 KB
    __shared__ f32x4 s_wn[NEXP][GCHUNK4];   // 16 KB

    const int w    = threadIdx.x >> 6;
    const int lane = threadIdx.x & 63;
    const int t0   = blockIdx.x * GATE_TPBK + w * GATE_TPW;   // wave's first token

    const f32x4* x0 = reinterpret_cast<const f32x4*>(x + (size_t)t0 * D_DIM);
    const f32x4* x1 = reinterpret_cast<const f32x4*>(x + (size_t)(t0 + 1) * D_DIM);

    float accg[GATE_TPW][NEXP];
    float accn[GATE_TPW][NEXP];
#pragma unroll
    for (int τ = 0; τ < GATE_TPW; ++τ)
#pragma unroll
        for (int e = 0; e < NEXP; ++e) { accg[τ][e] = 0.f; accn[τ][e] = 0.f; }

    for (int ch = 0; ch < NCHUNK; ++ch) {
        const int base4 = ch * GCHUNK4;
        // stage this chunk of both weight matrices (2048 f32x4, 4/thread)
#pragma unroll
        for (int j = threadIdx.x; j < NEXP * GCHUNK4; j += GATE_TPB) {
            const int e = j / GCHUNK4, c = j % GCHUNK4;
            s_wg[e][c] = reinterpret_cast<const f32x4*>(w_g     + (size_t)e * D_DIM)[base4 + c];
            s_wn[e][c] = reinterpret_cast<const f32x4*>(w_noise + (size_t)e * D_DIM)[base4 + c];
        }
        __syncthreads();

#pragma unroll
        for (int i = 0; i < GCHUNK4 / 64; ++i) {      // 2 iterations
            const int c = i * 64 + lane;
            const f32x4 xv0 = x0[base4 + c];
            const f32x4 xv1 = x1[base4 + c];
#pragma unroll
            for (int e = 0; e < NEXP; ++e) {
                const f32x4 g = s_wg[e][c];
                const f32x4 n = s_wn[e][c];
                accg[0][e] += dot4(xv0, g);
                accg[1][e] += dot4(xv1, g);
                accn[0][e] += dot4(xv0, n);
                accn[1][e] += dot4(xv1, n);
            }
        }
        __syncthreads();
    }

    // wave-wide reduction of the 32 accumulators
#pragma unroll
    for (int τ = 0; τ < GATE_TPW; ++τ)
#pragma unroll
        for (int e = 0; e < NEXP; ++e) {
            float vg = accg[τ][e], vn = accn[τ][e];
#pragma unroll
            for (int off = 32; off > 0; off >>= 1) {
                vg += __shfl_down(vg, off, 64);
                vn += __shfl_down(vn, off, 64);
            }
            accg[τ][e] = vg; accn[τ][e] = vn;   // valid on lane 0
        }

    if (lane == 0) {
#pragma unroll
        for (int τ = 0; τ < GATE_TPW; ++τ) {
            const int t = t0 + τ;
            float logit[NEXP];
#pragma unroll
            for (int e = 0; e < NEXP; ++e) {
                const float z = accn[τ][e];
                const float sp = fmaxf(z, 0.f) + log1pf(expf(-fabsf(z)));  // stable softplus
                logit[e] = accg[τ][e] + sp * noise[(size_t)t * NEXP + e];
            }
            // top-1 (strict > keeps first occurrence on ties, matches jax top_k)
            int i0 = 0; float v0 = logit[0];
#pragma unroll
            for (int e = 1; e < NEXP; ++e)
                if (logit[e] > v0) { v0 = logit[e]; i0 = e; }
            int i1 = -1; float v1 = -3.402823466e38f;
#pragma unroll
            for (int e = 0; e < NEXP; ++e)
                if (e != i0 && logit[e] > v1) { v1 = logit[e]; i1 = e; }
            const float e1  = expf(v1 - v0);
            const float inv = 1.f / (1.f + e1);
            top_idx[t]            = i0;
            top_idx[T_TOKENS + t] = i1;
            top_prob[t]            = inv;
            top_prob[T_TOKENS + t] = e1 * inv;
        }
    }
}

// ---------------------------------------------------------------------------
// Kernel 2: per-expert capacity scan + sparse scatter. One block per expert
// (8 blocks, 512 threads = 8 waves). Per-wave counts -> exclusive prefix ->
// rank pass that scatters the (weight, mask) scalars onto the memset-zeroed
// buffers and builds slot_token (its own range inited here, no memset).
// ---------------------------------------------------------------------------
__global__ void scan_scatter_kernel(const int*   __restrict__ top_idx,
                                    const float* __restrict__ top_prob,
                                    int*   __restrict__ slot_token,     // [NSLOTS]
                                    float* __restrict__ exp_weights,    // [T,8,CAP]
                                    float* __restrict__ exp_mask)       // [T,8,CAP]
{
    __shared__ int sidx[2 * T_TOKENS];   // 32 KB
    __shared__ int scnt[8];

    const int e    = blockIdx.x;         // expert
    const int w    = threadIdx.x >> 6;   // wave id (0..7)
    const int lane = threadIdx.x & 63;

    for (int i = threadIdx.x; i < 2 * T_TOKENS; i += 512)
        sidx[i] = top_idx[i];
    for (int r = threadIdx.x; r < CAP; r += 512)
        slot_token[e * CAP + r] = -1;
    __syncthreads();

    // phase A: wave w counts matches in its contiguous 16-chunk range
    int cnt = 0;
#pragma unroll
    for (int c = 0; c < 16; ++c) {
        const int i = (w * 16 + c) * 64 + lane;
        cnt += __popcll(__ballot(sidx[i] == e));
    }
    if (lane == 0) scnt[w] = cnt;
    __syncthreads();

    int base = 0;
#pragma unroll
    for (int j = 0; j < 8; ++j) if (j < w) base += scnt[j];

    // phase B: assign ranks, scatter scalars, build slot map
#pragma unroll
    for (int c = 0; c < 16; ++c) {
        const int i = (w * 16 + c) * 64 + lane;
        const bool match = (sidx[i] == e);
        const unsigned long long m = __ballot(match);
        if (match) {
            const int r = base + __popcll(m & ((1ull << lane) - 1ull));
            if (r < CAP) {
                slot_token[e * CAP + r] = i;
                const int t = i & (T_TOKENS - 1);
                const float wgt = top_prob[i];
                const size_t off = (size_t)t * NSLOTS + e * CAP + r;
                exp_weights[off] = wgt;
                exp_mask[off]    = (wgt != 0.f) ? 1.f : 0.f;
            }
        }
        base += __popcll(m);
    }
}

// ---------------------------------------------------------------------------
// Kernel 3: expert_batches — every byte written exactly once, plain stores.
// One block per (expert, cap) slot: copy x[t] if filled, zeros otherwise.
// x (33.5 MB) is L3-hot from gating (memset ran before gating on purpose).
// ---------------------------------------------------------------------------
__global__ void batches_kernel(const float* __restrict__ x,
                               const int*   __restrict__ slot_token,
                               float* __restrict__ expert_batches) // [8,CAP,D]
{
    const int slot = blockIdx.x;          // e*CAP + r
    const int i = slot_token[slot];
    f32x4* dst = reinterpret_cast<f32x4*>(expert_batches + (size_t)slot * D_DIM);

    if (i >= 0) {
        const int t = i & (T_TOKENS - 1);
        const f32x4* src = reinterpret_cast<const f32x4*>(x + (size_t)t * D_DIM);
#pragma unroll
        for (int c = threadIdx.x; c < D_DIM / 4; c += 256)
            dst[c] = src[c];
    } else {
        const f32x4 z = {0.f, 0.f, 0.f, 0.f};
#pragma unroll
        for (int c = threadIdx.x; c < D_DIM / 4; c += 256)
            dst[c] = z;
    }
}

// ---------------------------------------------------------------------------
extern "C" void kernel_launch(void* const* d_in, const int* in_sizes, int n_in,
                              void* d_out, int out_size, void* d_ws, size_t ws_size,
                              hipStream_t stream)
{
    const float* x       = (const float*)d_in[0];
    const float* noise   = (const float*)d_in[1];
    const float* w_g     = (const float*)d_in[2];
    const float* w_noise = (const float*)d_in[3];

    float* out = (float*)d_out;
    const size_t n_ew = (size_t)T_TOKENS * NEXP * CAP;   // 41,943,040
    float* exp_weights    = out;
    float* exp_mask       = out + n_ew;
    float* expert_batches = out + 2 * n_ew;

    int*   top_idx    = (int*)d_ws;                                      // 8192 ints
    float* top_prob   = (float*)((char*)d_ws + 2 * T_TOKENS * 4);        // 8192 floats
    int*   slot_token = (int*)((char*)d_ws + 4 * T_TOKENS * 4);          // 10240 ints

    // zero weights+mask (contiguous 335.5 MB) with the rocclr fill — it
    // demonstrably sustains ~7 TB/s on this buffer, beating our own writer.
    // Runs FIRST so x stays L3-hot from gating into the batches gather.
    (void)hipMemsetAsync(out, 0, 2 * n_ew * sizeof(float), stream);

    gating_kernel<<<GATE_BLOCKS, GATE_TPB, 0, stream>>>(x, noise, w_g, w_noise,
                                                        top_idx, top_prob);
    scan_scatter_kernel<<<NEXP, 512, 0, stream>>>(top_idx, top_prob, slot_token,
                                                  exp_weights, exp_mask);
    batches_kernel<<<NSLOTS, 256, 0, stream>>>(x, slot_token, expert_batches);
}

// Round 10
// 131.231 us; speedup vs baseline: 1.0312x; 1.0312x over previous
//
#include <hip/hip_runtime.h>
#include <stdint.h>

// Problem constants (from reference)
#define T_TOKENS 4096      // B*C = 4*1024
#define D_DIM    2048
#define NEXP     8
#define CAP      1280      // floor(2 * 1.25 * 4096 / 8), already even
#define NSLOTS   (NEXP * CAP)   // 10240

// gating geometry
#define GATE_TPB   512                       // 8 waves
#define GATE_TPW   2                         // tokens per wave
#define GATE_TPBK  16                        // tokens per block
#define GATE_BLOCKS (T_TOKENS / GATE_TPBK)   // 256
#define GCHUNK     512                       // floats of D per LDS stage
#define GCHUNK4    (GCHUNK / 4)              // 128 f32x4
#define NCHUNK     (D_DIM / GCHUNK)          // 4

// native 16-byte vector type
typedef float f32x4 __attribute__((ext_vector_type(4)));

__device__ __forceinline__ float dot4(f32x4 a, f32x4 b) {
    return a.x * b.x + a.y * b.y + a.z * b.z + a.w * b.w;
}

// Streaming store: system-scope + non-temporal -> write past/through L2.
// Same bytes as a plain store; only cache policy differs. Kernel-end release
// fence (s_waitcnt vmcnt(0)) covers these before dispatch-complete.
__device__ __forceinline__ void stream_store(f32x4* p, f32x4 v) {
    asm volatile("global_store_dwordx4 %0, %1, off sc0 sc1 nt"
                 :: "v"(p), "v"(v) : "memory");
}

// ---------------------------------------------------------------------------
// Kernel 1: gating with LDS-staged weights (proven in round 9). 256 blocks x
// 512 threads, 16 tokens/block, 2 tokens/wave; weights staged in 32 KB LDS
// chunks so L2 weight traffic is 16x lower than one-wave-per-token.
// ---------------------------------------------------------------------------
__global__ void gating_kernel(const float* __restrict__ x,
                              const float* __restrict__ noise,
                              const float* __restrict__ w_g,
                              const float* __restrict__ w_noise,
                              int*   __restrict__ top_idx,    // [2*T] slot-major
                              float* __restrict__ top_prob)   // [2*T] slot-major
{
    __shared__ f32x4 s_wg[NEXP][GCHUNK4];   // 16 KB
    __shared__ f32x4 s_wn[NEXP][GCHUNK4];   // 16 KB

    const int w    = threadIdx.x >> 6;
    const int lane = threadIdx.x & 63;
    const int t0   = blockIdx.x * GATE_TPBK + w * GATE_TPW;   // wave's first token

    const f32x4* x0 = reinterpret_cast<const f32x4*>(x + (size_t)t0 * D_DIM);
    const f32x4* x1 = reinterpret_cast<const f32x4*>(x + (size_t)(t0 + 1) * D_DIM);

    float accg[GATE_TPW][NEXP];
    float accn[GATE_TPW][NEXP];
#pragma unroll
    for (int q = 0; q < GATE_TPW; ++q)
#pragma unroll
        for (int e = 0; e < NEXP; ++e) { accg[q][e] = 0.f; accn[q][e] = 0.f; }

    for (int ch = 0; ch < NCHUNK; ++ch) {
        const int base4 = ch * GCHUNK4;
#pragma unroll
        for (int j = threadIdx.x; j < NEXP * GCHUNK4; j += GATE_TPB) {
            const int e = j / GCHUNK4, c = j % GCHUNK4;
            s_wg[e][c] = reinterpret_cast<const f32x4*>(w_g     + (size_t)e * D_DIM)[base4 + c];
            s_wn[e][c] = reinterpret_cast<const f32x4*>(w_noise + (size_t)e * D_DIM)[base4 + c];
        }
        __syncthreads();

#pragma unroll
        for (int i = 0; i < GCHUNK4 / 64; ++i) {      // 2 iterations
            const int c = i * 64 + lane;
            const f32x4 xv0 = x0[base4 + c];
            const f32x4 xv1 = x1[base4 + c];
#pragma unroll
            for (int e = 0; e < NEXP; ++e) {
                const f32x4 g = s_wg[e][c];
                const f32x4 n = s_wn[e][c];
                accg[0][e] += dot4(xv0, g);
                accg[1][e] += dot4(xv1, g);
                accn[0][e] += dot4(xv0, n);
                accn[1][e] += dot4(xv1, n);
            }
        }
        __syncthreads();
    }

#pragma unroll
    for (int q = 0; q < GATE_TPW; ++q)
#pragma unroll
        for (int e = 0; e < NEXP; ++e) {
            float vg = accg[q][e], vn = accn[q][e];
#pragma unroll
            for (int off = 32; off > 0; off >>= 1) {
                vg += __shfl_down(vg, off, 64);
                vn += __shfl_down(vn, off, 64);
            }
            accg[q][e] = vg; accn[q][e] = vn;   // valid on lane 0
        }

    if (lane == 0) {
#pragma unroll
        for (int q = 0; q < GATE_TPW; ++q) {
            const int t = t0 + q;
            float logit[NEXP];
#pragma unroll
            for (int e = 0; e < NEXP; ++e) {
                const float z = accn[q][e];
                const float sp = fmaxf(z, 0.f) + log1pf(expf(-fabsf(z)));  // stable softplus
                logit[e] = accg[q][e] + sp * noise[(size_t)t * NEXP + e];
            }
            // top-1 / top-2 (strict > keeps lowest index on ties = jax top_k)
            int i0 = 0; float v0 = logit[0];
#pragma unroll
            for (int e = 1; e < NEXP; ++e)
                if (logit[e] > v0) { v0 = logit[e]; i0 = e; }
            int i1 = -1; float v1 = -3.402823466e38f;
#pragma unroll
            for (int e = 0; e < NEXP; ++e)
                if (e != i0 && logit[e] > v1) { v1 = logit[e]; i1 = e; }
            const float e1  = expf(v1 - v0);
            const float inv = 1.f / (1.f + e1);
            top_idx[t]            = i0;
            top_idx[T_TOKENS + t] = i1;
            top_prob[t]            = inv;
            top_prob[T_TOKENS + t] = e1 * inv;
        }
    }
}

// ---------------------------------------------------------------------------
// Kernel 2: per-expert capacity scan. One block per expert (8 blocks, 512
// threads = 8 waves). Per-wave counts -> exclusive prefix -> rank pass.
// Outputs rank[2T] (-1 if dropped) and slot_token[NSLOTS] (-1 if empty).
// ---------------------------------------------------------------------------
__global__ void scan_kernel(const int* __restrict__ top_idx,
                            int* __restrict__ rank,          // [2*T]
                            int* __restrict__ slot_token)    // [NSLOTS]
{
    __shared__ int sidx[2 * T_TOKENS];   // 32 KB
    __shared__ int scnt[8];

    const int e    = blockIdx.x;         // expert
    const int w    = threadIdx.x >> 6;   // wave id (0..7)
    const int lane = threadIdx.x & 63;

    for (int i = threadIdx.x; i < 2 * T_TOKENS; i += 512)
        sidx[i] = top_idx[i];
    for (int r = threadIdx.x; r < CAP; r += 512)
        slot_token[e * CAP + r] = -1;
    __syncthreads();

    int cnt = 0;
#pragma unroll
    for (int c = 0; c < 16; ++c) {
        const int i = (w * 16 + c) * 64 + lane;
        cnt += __popcll(__ballot(sidx[i] == e));
    }
    if (lane == 0) scnt[w] = cnt;
    __syncthreads();

    int base = 0;
#pragma unroll
    for (int j = 0; j < 8; ++j) if (j < w) base += scnt[j];

#pragma unroll
    for (int c = 0; c < 16; ++c) {
        const int i = (w * 16 + c) * 64 + lane;
        const bool match = (sidx[i] == e);
        const unsigned long long m = __ballot(match);
        if (match) {
            const int r = base + __popcll(m & ((1ull << lane) - 1ull));
            const bool keep = (r < CAP);
            rank[i] = keep ? r : -1;
            if (keep) slot_token[e * CAP + r] = i;
        }
        base += __popcll(m);
    }
}

// ---------------------------------------------------------------------------
// Kernel 3 (fused writer): every output byte written exactly once with its
// final value, via streaming (sc0 sc1 nt) stores. Block ranges:
//   [0, NSLOTS)            : expert_batches row (gather x, L3-hot, or zeros)
//   [NSLOTS, NSLOTS+T)     : exp_weights row
//   [NSLOTS+T, NSLOTS+2T)  : exp_mask row
// ---------------------------------------------------------------------------
__global__ void writer_kernel(const float* __restrict__ x,
                              const int*   __restrict__ top_idx,
                              const float* __restrict__ top_prob,
                              const int*   __restrict__ rank,
                              const int*   __restrict__ slot_token,
                              float* __restrict__ exp_weights,    // [T,8,CAP]
                              float* __restrict__ exp_mask,       // [T,8,CAP]
                              float* __restrict__ expert_batches) // [8,CAP,D]
{
    const int bid = blockIdx.x;

    if (bid < NSLOTS) {
        // ---- expert_batches row ----
        const int slot = bid;                 // e*CAP + r
        const int i = slot_token[slot];
        f32x4* dst = reinterpret_cast<f32x4*>(expert_batches + (size_t)slot * D_DIM);

        if (i >= 0) {
            const int t = i & (T_TOKENS - 1);
            const f32x4* src = reinterpret_cast<const f32x4*>(x + (size_t)t * D_DIM);
#pragma unroll
            for (int c = threadIdx.x; c < D_DIM / 4; c += 256)
                stream_store(dst + c, src[c]);
        } else {
            const f32x4 z = {0.f, 0.f, 0.f, 0.f};
#pragma unroll
            for (int c = threadIdx.x; c < D_DIM / 4; c += 256)
                stream_store(dst + c, z);
        }
        return;
    }

    // ---- weights / mask row for token t ----
    const bool is_mask = (bid >= NSLOTS + T_TOKENS);
    const int t = bid - NSLOTS - (is_mask ? T_TOKENS : 0);

    const int e0 = top_idx[t];
    const int e1 = top_idx[T_TOKENS + t];
    const int r0 = rank[t];
    const int r1 = rank[T_TOKENS + t];
    const float w0 = top_prob[t];
    const float w1 = top_prob[T_TOKENS + t];

    const int p0 = (r0 >= 0) ? (e0 * CAP + r0) : -1;
    const int p1 = (r1 >= 0) ? (e1 * CAP + r1) : -1;
    // mask semantics: exp_mask_out = (exp_weights != 0)
    const float v0 = is_mask ? ((w0 != 0.f) ? 1.f : 0.f) : w0;
    const float v1 = is_mask ? ((w1 != 0.f) ? 1.f : 0.f) : w1;

    float* base = is_mask ? exp_mask : exp_weights;
    f32x4* out = reinterpret_cast<f32x4*>(base + (size_t)t * NSLOTS);

#pragma unroll
    for (int f = threadIdx.x; f < NSLOTS / 4; f += 256) {
        const int b = 4 * f;
        f32x4 v;
        v.x = (b     == p0) ? v0 : (b     == p1) ? v1 : 0.f;
        v.y = (b + 1 == p0) ? v0 : (b + 1 == p1) ? v1 : 0.f;
        v.z = (b + 2 == p0) ? v0 : (b + 2 == p1) ? v1 : 0.f;
        v.w = (b + 3 == p0) ? v0 : (b + 3 == p1) ? v1 : 0.f;
        stream_store(out + f, v);
    }
}

// ---------------------------------------------------------------------------
extern "C" void kernel_launch(void* const* d_in, const int* in_sizes, int n_in,
                              void* d_out, int out_size, void* d_ws, size_t ws_size,
                              hipStream_t stream)
{
    const float* x       = (const float*)d_in[0];
    const float* noise   = (const float*)d_in[1];
    const float* w_g     = (const float*)d_in[2];
    const float* w_noise = (const float*)d_in[3];

    float* out = (float*)d_out;
    const size_t n_ew = (size_t)T_TOKENS * NEXP * CAP;   // 41,943,040
    float* exp_weights    = out;
    float* exp_mask       = out + n_ew;
    float* expert_batches = out + 2 * n_ew;

    int*   top_idx    = (int*)d_ws;                                      // 8192 ints
    float* top_prob   = (float*)((char*)d_ws + 2 * T_TOKENS * 4);        // 8192 floats
    int*   rank       = (int*)((char*)d_ws + 4 * T_TOKENS * 4);          // 8192 ints
    int*   slot_token = (int*)((char*)d_ws + 6 * T_TOKENS * 4);          // 10240 ints

    gating_kernel<<<GATE_BLOCKS, GATE_TPB, 0, stream>>>(x, noise, w_g, w_noise,
                                                        top_idx, top_prob);
    scan_kernel<<<NEXP, 512, 0, stream>>>(top_idx, rank, slot_token);
    writer_kernel<<<NSLOTS + 2 * T_TOKENS, 256, 0, stream>>>(
        x, top_idx, top_prob, rank, slot_token,
        exp_weights, exp_mask, expert_batches);
}

// Round 12
// 123.734 us; speedup vs baseline: 1.0937x; 1.0606x over previous
//
#include <hip/hip_runtime.h>

// Problem constants (from reference)
#define T_TOKENS 4096      // B*C = 4*1024
#define D_DIM    2048
#define NEXP     8
#define CAP      1280      // floor(2 * 1.25 * 4096 / 8), already even
#define NSLOTS   (NEXP * CAP)   // 10240

#define GATE_BLOCKS (T_TOKENS / 4)               // 1024
#define FILL_FLOATS (2ull * T_TOKENS * NSLOTS)   // exp_weights + exp_mask = 83,886,080
#define FILL_VECS   (FILL_FLOATS / 4)            // 20,971,520 f32x4
#define FILL_BLOCKS 5120
#define FILL_THREADS (FILL_BLOCKS * 256)         // 1,310,720 -> 16 stores/thread

// native 16-byte vector type
typedef float f32x4 __attribute__((ext_vector_type(4)));

// ---------------------------------------------------------------------------
// Kernel 1 (fused): blocks [0, GATE_BLOCKS) run gating (4 tokens each, one
// wave per token); remaining FILL_BLOCKS zero-fill exp_weights + exp_mask
// with a rocclr-style grid-stride pattern and plain stores.
// (Exact r5 structure — best passing measurement, 118.99 us.)
// ---------------------------------------------------------------------------
__global__ void gate_fill_kernel(const float* __restrict__ x,
                                 const float* __restrict__ noise,
                                 const float* __restrict__ w_g,
                                 const float* __restrict__ w_noise,
                                 int*   __restrict__ top_idx,    // [2*T] slot-major
                                 float* __restrict__ top_prob,   // [2*T] slot-major
                                 float* __restrict__ wm_base)    // exp_weights (mask follows)
{
    if (blockIdx.x >= GATE_BLOCKS) {
        // ---- zero-fill portion: grid-stride, plain stores ----
        const size_t tid = (size_t)(blockIdx.x - GATE_BLOCKS) * 256 + threadIdx.x;
        f32x4* dst = reinterpret_cast<f32x4*>(wm_base);
        const f32x4 z = {0.f, 0.f, 0.f, 0.f};
#pragma unroll
        for (int j = 0; j < (int)(FILL_VECS / FILL_THREADS); ++j)
            dst[(size_t)j * FILL_THREADS + tid] = z;
        return;
    }

    // ---- gating portion ----
    const int wave = threadIdx.x >> 6;
    const int lane = threadIdx.x & 63;
    const int t = blockIdx.x * 4 + wave;

    const f32x4* xv = reinterpret_cast<const f32x4*>(x + (size_t)t * D_DIM);

    float acc[16];
#pragma unroll
    for (int j = 0; j < 16; ++j) acc[j] = 0.f;

#pragma unroll
    for (int it = 0; it < 8; ++it) {
        const int c = it * 64 + lane;   // float4 column index
        const f32x4 xval = xv[c];
#pragma unroll
        for (int e = 0; e < NEXP; ++e) {
            const f32x4 g = reinterpret_cast<const f32x4*>(w_g + (size_t)e * D_DIM)[c];
            acc[e] += xval.x * g.x + xval.y * g.y + xval.z * g.z + xval.w * g.w;
            const f32x4 n = reinterpret_cast<const f32x4*>(w_noise + (size_t)e * D_DIM)[c];
            acc[8 + e] += xval.x * n.x + xval.y * n.y + xval.z * n.z + xval.w * n.w;
        }
    }

#pragma unroll
    for (int j = 0; j < 16; ++j) {
        float v = acc[j];
#pragma unroll
        for (int off = 32; off > 0; off >>= 1) v += __shfl_down(v, off, 64);
        acc[j] = v;   // valid on lane 0
    }

    if (lane == 0) {
        float logit[NEXP];
#pragma unroll
        for (int e = 0; e < NEXP; ++e) {
            const float z = acc[8 + e];
            const float sp = fmaxf(z, 0.f) + log1pf(expf(-fabsf(z)));  // stable softplus
            logit[e] = acc[e] + sp * noise[(size_t)t * NEXP + e];
        }
        int i0 = 0; float v0 = logit[0];
#pragma unroll
        for (int e = 1; e < NEXP; ++e) {
            if (logit[e] > v0) { v0 = logit[e]; i0 = e; }
        }
        int i1 = -1; float v1 = -3.402823466e38f;
#pragma unroll
        for (int e = 0; e < NEXP; ++e) {
            if (e != i0 && logit[e] > v1) { v1 = logit[e]; i1 = e; }
        }
        const float e1  = expf(v1 - v0);
        const float inv = 1.f / (1.f + e1);
        top_idx[t]            = i0;
        top_idx[T_TOKENS + t] = i1;
        top_prob[t]            = inv;
        top_prob[T_TOKENS + t] = e1 * inv;
    }
}

// ---------------------------------------------------------------------------
// Kernel 2: per-expert capacity scan + sparse scatter. One block per expert
// (8 blocks, 512 threads = 8 waves). Per-wave counts -> exclusive prefix ->
// rank pass that scatters the (weight, mask) scalars onto the zeroed
// buffers and builds slot_token (its own range inited, no memset).
// ---------------------------------------------------------------------------
__global__ void scan_scatter_kernel(const int*   __restrict__ top_idx,
                                    const float* __restrict__ top_prob,
                                    int*   __restrict__ slot_token,     // [NSLOTS]
                                    float* __restrict__ exp_weights,    // [T,8,CAP]
                                    float* __restrict__ exp_mask)       // [T,8,CAP]
{
    __shared__ int sidx[2 * T_TOKENS];   // 32 KB
    __shared__ int scnt[8];

    const int e    = blockIdx.x;         // expert
    const int w    = threadIdx.x >> 6;   // wave id (0..7)
    const int lane = threadIdx.x & 63;

    for (int i = threadIdx.x; i < 2 * T_TOKENS; i += 512)
        sidx[i] = top_idx[i];
    for (int r = threadIdx.x; r < CAP; r += 512)
        slot_token[e * CAP + r] = -1;
    __syncthreads();

    // phase A: wave w counts matches in its contiguous 16-chunk range
    int cnt = 0;
#pragma unroll
    for (int c = 0; c < 16; ++c) {
        const int i = (w * 16 + c) * 64 + lane;
        cnt += __popcll(__ballot(sidx[i] == e));
    }
    if (lane == 0) scnt[w] = cnt;
    __syncthreads();

    int base = 0;
#pragma unroll
    for (int j = 0; j < 8; ++j) if (j < w) base += scnt[j];

    // phase B: assign ranks, scatter scalars, build slot map
#pragma unroll
    for (int c = 0; c < 16; ++c) {
        const int i = (w * 16 + c) * 64 + lane;
        const bool match = (sidx[i] == e);
        const unsigned long long m = __ballot(match);
        if (match) {
            const int r = base + __popcll(m & ((1ull << lane) - 1ull));
            if (r < CAP) {
                slot_token[e * CAP + r] = i;
                const int t = i & (T_TOKENS - 1);
                const float wgt = top_prob[i];
                const size_t off = (size_t)t * NSLOTS + e * CAP + r;
                exp_weights[off] = wgt;
                exp_mask[off]    = (wgt != 0.f) ? 1.f : 0.f;
            }
        }
        base += __popcll(m);
    }
}

// ---------------------------------------------------------------------------
// Kernel 3: expert_batches — every byte written exactly once, plain stores.
// One block per (expert, cap) slot: copy x[t] if filled, zeros otherwise.
// ---------------------------------------------------------------------------
__global__ void batches_kernel(const float* __restrict__ x,
                               const int*   __restrict__ slot_token,
                               float* __restrict__ expert_batches) // [8,CAP,D]
{
    const int slot = blockIdx.x;          // e*CAP + r
    const int i = slot_token[slot];
    f32x4* dst = reinterpret_cast<f32x4*>(expert_batches + (size_t)slot * D_DIM);

    if (i >= 0) {
        const int t = i & (T_TOKENS - 1);
        const f32x4* src = reinterpret_cast<const f32x4*>(x + (size_t)t * D_DIM);
#pragma unroll
        for (int c = threadIdx.x; c < D_DIM / 4; c += 256)
            dst[c] = src[c];
    } else {
        const f32x4 z = {0.f, 0.f, 0.f, 0.f};
#pragma unroll
        for (int c = threadIdx.x; c < D_DIM / 4; c += 256)
            dst[c] = z;
    }
}

// ---------------------------------------------------------------------------
extern "C" void kernel_launch(void* const* d_in, const int* in_sizes, int n_in,
                              void* d_out, int out_size, void* d_ws, size_t ws_size,
                              hipStream_t stream)
{
    const float* x       = (const float*)d_in[0];
    const float* noise   = (const float*)d_in[1];
    const float* w_g     = (const float*)d_in[2];
    const float* w_noise = (const float*)d_in[3];

    float* out = (float*)d_out;
    const size_t n_ew = (size_t)T_TOKENS * NEXP * CAP;   // 41,943,040
    float* exp_weights    = out;
    float* exp_mask       = out + n_ew;
    float* expert_batches = out + 2 * n_ew;

    int*   top_idx    = (int*)d_ws;                                      // 8192 ints
    float* top_prob   = (float*)((char*)d_ws + 2 * T_TOKENS * 4);        // 8192 floats
    int*   slot_token = (int*)((char*)d_ws + 4 * T_TOKENS * 4);          // 10240 ints

    gate_fill_kernel<<<GATE_BLOCKS + FILL_BLOCKS, 256, 0, stream>>>(
        x, noise, w_g, w_noise, top_idx, top_prob, exp_weights);
    scan_scatter_kernel<<<NEXP, 512, 0, stream>>>(top_idx, top_prob, slot_token,
                                                  exp_weights, exp_mask);
    batches_kernel<<<NSLOTS, 256, 0, stream>>>(x, slot_token, expert_batches);
}